// Round 8
// baseline (211.085 us; speedup 1.0000x reference)
//
#include <hip/hip_runtime.h>
#include <math.h>

#define N_NODES 20000
#define IN_DIM  512
#define HID     128
#define HEADS   8
#define C_DIM   16
#define LAYERS  2
#define NEDGE   320000
#define NEG_SLOPE 0.2f
#define LN_EPS  1e-5f
#define CAP     64   // ELL capacity (incl. self loop); deg ~ Poisson(16)
#define SLOTS   32   // edge slots per k_gat chunk -> 1 gather round for deg+1 <= 32

typedef __attribute__((ext_vector_type(8))) short short8;
typedef __attribute__((ext_vector_type(4))) float f32x4;

__device__ __forceinline__ unsigned short f2bf(float f) {
    unsigned int u = __float_as_uint(f);
    u += 0x7fffu + ((u >> 16) & 1u);
    return (unsigned short)(u >> 16);
}
__device__ __forceinline__ float bf2f(unsigned short s) {
    return __uint_as_float(((unsigned int)s) << 16);
}

// ------- one-time: weights -> bf16 transposed [n][k]; cnt=1 + self-loop in adj -------
__global__ __launch_bounds__(256) void k_convert(
    const float* __restrict__ W_in, const float* __restrict__ Wl, const float* __restrict__ Wr,
    unsigned short* __restrict__ WtI, unsigned short* __restrict__ Wlt, unsigned short* __restrict__ Wrt,
    int* __restrict__ cnt, int* __restrict__ adj)
{
    int i = blockIdx.x * 256 + threadIdx.x;
    if (i < N_NODES) { cnt[i] = 1; adj[(size_t)i * CAP] = i; }   // self loop at slot 0
    if (i < 65536) {                      // WtI[128][512]
        int n = i >> 9, k = i & 511;
        WtI[i] = f2bf(W_in[k * HID + n]);
    } else if (i < 98304) {               // Wlt[L][128][128]
        int r = i - 65536;
        int L = r >> 14, q = r & 16383;
        int n = q >> 7, k = q & 127;
        Wlt[r] = f2bf(Wl[L * 16384 + k * HID + n]);
    } else if (i < 131072) {              // Wrt[L][128][128]
        int r = i - 98304;
        int L = r >> 14, q = r & 16383;
        int n = q >> 7, k = q & 127;
        Wrt[r] = f2bf(Wr[L * 16384 + k * HID + n]);
    }
}

__global__ __launch_bounds__(256) void k_build(
    const int* __restrict__ ei, int* __restrict__ cnt, int* __restrict__ adj)
{
    int e = blockIdx.x * 256 + threadIdx.x;
    if (e >= NEDGE) return;
    int src = ei[e];
    int dst = ei[NEDGE + e];
    int r = atomicAdd(&cnt[dst], 1);
    if (r < CAP) adj[(size_t)dst * CAP + r] = src;
}

// ------- input proj MFMA: h = relu(LN(x @ W_in + b)), also hb = bf16(h) -------
__global__ __launch_bounds__(128) void k_proj(
    const float* __restrict__ x, const unsigned short* __restrict__ WtI,
    const float* __restrict__ b, const float* __restrict__ g, const float* __restrict__ beta,
    float* __restrict__ h, unsigned short* __restrict__ hb)
{
    __shared__ unsigned short wlds[128][136];   // [n][k-chunk]
    __shared__ unsigned short xtile[32][136];   // [row][k-chunk] bf16
    const int tid = threadIdx.x;
    const int wid = tid >> 6;
    const int l   = tid & 63;
    const int grp = l >> 4;
    const int ln  = l & 15;
    const int row0 = blockIdx.x * 32;

    f32x4 acc[8];
#pragma unroll
    for (int j = 0; j < 8; ++j) acc[j] = (f32x4){0.f, 0.f, 0.f, 0.f};

    const int sr = tid >> 4;
    const int sc = (tid & 15) * 8;
    const int xrr = tid >> 2;            // x staging: row
    const int xcc = (tid & 3) * 32;      // x staging: col base

    for (int kc = 0; kc < 4; ++kc) {
        __syncthreads();
#pragma unroll
        for (int rr = sr; rr < 128; rr += 8)
            *(short8*)&wlds[rr][sc] = *(const short8*)&WtI[rr * IN_DIM + kc * 128 + sc];
        {
            const float4* ps = (const float4*)&x[(size_t)(row0 + xrr) * IN_DIM + kc * 128 + xcc];
#pragma unroll
            for (int q = 0; q < 4; ++q) {
                float4 va = ps[2 * q], vb = ps[2 * q + 1];
                short8 o;
                o[0] = (short)f2bf(va.x); o[1] = (short)f2bf(va.y);
                o[2] = (short)f2bf(va.z); o[3] = (short)f2bf(va.w);
                o[4] = (short)f2bf(vb.x); o[5] = (short)f2bf(vb.y);
                o[6] = (short)f2bf(vb.z); o[7] = (short)f2bf(vb.w);
                *(short8*)&xtile[xrr][xcc + q * 8] = o;
            }
        }
        __syncthreads();
#pragma unroll
        for (int ks = 0; ks < 4; ++ks) {
            short8 a = *(short8*)&xtile[wid * 16 + ln][ks * 32 + grp * 8];
#pragma unroll
            for (int j = 0; j < 8; ++j) {
                short8 bf = *(short8*)&wlds[j * 16 + ln][ks * 32 + grp * 8];
                acc[j] = __builtin_amdgcn_mfma_f32_16x16x32_bf16(a, bf, acc[j], 0, 0, 0);
            }
        }
    }
    // epilogue: +bias, LN over 128 cols, ReLU
    float s1[4] = {0, 0, 0, 0}, s2[4] = {0, 0, 0, 0};
#pragma unroll
    for (int j = 0; j < 8; ++j) {
        float bb = b[j * 16 + ln];
#pragma unroll
        for (int r = 0; r < 4; ++r) {
            float v = acc[j][r] + bb;
            acc[j][r] = v;
            s1[r] += v; s2[r] += v * v;
        }
    }
#pragma unroll
    for (int r = 0; r < 4; ++r) {
#pragma unroll
        for (int off = 8; off; off >>= 1) {
            s1[r] += __shfl_xor(s1[r], off);
            s2[r] += __shfl_xor(s2[r], off);
        }
    }
#pragma unroll
    for (int r = 0; r < 4; ++r) {
        float mu  = s1[r] * (1.f / HID);
        float var = s2[r] * (1.f / HID) - mu * mu;
        float rs  = rsqrtf(var + LN_EPS);
        int row = row0 + wid * 16 + grp * 4 + r;
#pragma unroll
        for (int j = 0; j < 8; ++j) {
            int c = j * 16 + ln;
            float o = (acc[j][r] - mu) * rs * g[c] + beta[c];
            o = fmaxf(o, 0.f);
            h [(size_t)row * HID + c] = o;
            hb[(size_t)row * HID + c] = f2bf(o);
        }
    }
}

// ------- per-layer MFMA: xlb = bf16(hb@Wl + bl) ; xrb = bf16(hb@Wr + br) -------
// B-fragments read directly from global (64 KB hot set, L1/L2-resident) - no LDS.
__global__ __launch_bounds__(128) void k_xlxr(
    const unsigned short* __restrict__ hb,
    const unsigned short* __restrict__ Wlt, const unsigned short* __restrict__ Wrt,
    const float* __restrict__ bl, const float* __restrict__ br,
    unsigned short* __restrict__ xlb, unsigned short* __restrict__ xrb)
{
    const int tid = threadIdx.x;
    const int wid = tid >> 6;
    const int l   = tid & 63;
    const int grp = l >> 4;
    const int ln  = l & 15;
    const int row0 = blockIdx.x * 32;
    const int arow = row0 + wid * 16 + ln;

    short8 a[4];
#pragma unroll
    for (int ks = 0; ks < 4; ++ks)
        a[ks] = *(const short8*)&hb[(size_t)arow * HID + ks * 32 + grp * 8];

    f32x4 aL[8], aR[8];
#pragma unroll
    for (int j = 0; j < 8; ++j) {
        aL[j] = (f32x4){0.f, 0.f, 0.f, 0.f};
        aR[j] = (f32x4){0.f, 0.f, 0.f, 0.f};
    }
#pragma unroll
    for (int j = 0; j < 8; ++j) {
        const unsigned short* pl = &Wlt[(size_t)(j * 16 + ln) * HID + grp * 8];
        const unsigned short* pr = &Wrt[(size_t)(j * 16 + ln) * HID + grp * 8];
#pragma unroll
        for (int ks = 0; ks < 4; ++ks) {
            short8 b8l = *(const short8*)&pl[ks * 32];
            aL[j] = __builtin_amdgcn_mfma_f32_16x16x32_bf16(a[ks], b8l, aL[j], 0, 0, 0);
            short8 b8r = *(const short8*)&pr[ks * 32];
            aR[j] = __builtin_amdgcn_mfma_f32_16x16x32_bf16(a[ks], b8r, aR[j], 0, 0, 0);
        }
    }
#pragma unroll
    for (int r = 0; r < 4; ++r) {
        int row = row0 + wid * 16 + grp * 4 + r;
#pragma unroll
        for (int j = 0; j < 8; ++j) {
            int c = j * 16 + ln;
            xlb[(size_t)row * HID + c] = f2bf(aL[j][r] + bl[c]);
            xrb[(size_t)row * HID + c] = f2bf(aR[j][r] + br[c]);
        }
    }
}

// ------- fused GAT layer: 32 slots x 8 heads, single gather round, swizzled reduce -------
// thread (e,hh) = (t>>3, t&7): edge-slot e (0..31), head hh, channels [hh*16, hh*16+16)
__global__ __launch_bounds__(256) void k_gat(
    const unsigned short* __restrict__ xlb, const unsigned short* __restrict__ xrb,
    const int* __restrict__ adj, const int* __restrict__ cnt,
    const float* __restrict__ att, const float* __restrict__ gbias,
    const float* __restrict__ g, const float* __restrict__ beta,
    const float* __restrict__ hin, float* __restrict__ hout,
    unsigned short* __restrict__ hbout)
{
    __shared__ int   adjs[CAP];
    __shared__ float lacc[SLOTS][132];   // row stride 33 float4s (odd) -> bank spread
    __shared__ float ls[SLOTS][HEADS];
    __shared__ float tmp[4];
    __shared__ int   deg_s;
    const int d  = blockIdx.x;
    const int t  = threadIdx.x;
    const int e  = t >> 3;
    const int hh = t & 7;
    const int cb = hh * 16;

    if (t == 0) deg_s = min(cnt[d], CAP);
    if (t < CAP) adjs[t] = adj[(size_t)d * CAP + t];
    __syncthreads();
    const int nj = deg_s;               // includes self loop at slot 0

    float av[16], rv[16];
#pragma unroll
    for (int q = 0; q < 4; ++q) {
        float4 a4 = *(const float4*)&att[cb + q * 4];
        av[q*4+0] = a4.x; av[q*4+1] = a4.y; av[q*4+2] = a4.z; av[q*4+3] = a4.w;
    }
    {
        const short8* pr = (const short8*)&xrb[(size_t)d * HID + cb];
        short8 r0 = pr[0], r1 = pr[1];
#pragma unroll
        for (int q = 0; q < 8; ++q) {
            rv[q]     = bf2f((unsigned short)r0[q]);
            rv[8 + q] = bf2f((unsigned short)r1[q]);
        }
    }

    float acc[16];
#pragma unroll
    for (int q = 0; q < 16; ++q) acc[q] = 0.f;
    float s_part = 0.f;

    const int nchunk = (nj + SLOTS - 1) >> 5;   // == 1 for deg+1 <= 32 (~99.99%)
    for (int ch = 0; ch < nchunk; ++ch) {
        int j = ch * SLOTS + e;
        int srcn = adjs[j < nj ? j : 0];
        const short8* px = (const short8*)&xlb[(size_t)srcn * HID + cb];
        short8 x0 = px[0], x1 = px[1];
        float xf[16];
#pragma unroll
        for (int q = 0; q < 8; ++q) {
            xf[q]     = bf2f((unsigned short)x0[q]);
            xf[8 + q] = bf2f((unsigned short)x1[q]);
        }
        float ll = 0.f;
#pragma unroll
        for (int q = 0; q < 16; ++q) {
            float u = xf[q] + rv[q];
            u = fmaxf(u, NEG_SLOPE * u);
            ll = fmaf(av[q], u, ll);
        }
        // exp without max-shift: logits O(+-10), identical softmax result
        float p = (j < nj) ? __expf(ll) : 0.f;
        s_part += p;
#pragma unroll
        for (int q = 0; q < 16; ++q) acc[q] = fmaf(p, xf[q], acc[q]);
    }

    // swizzled-column float4 store (proven in R7): content quad q of head hh
    // lives at physical quad 4*hh + ((q+(hh>>1))&3)
#pragma unroll
    for (int q = 0; q < 4; ++q) {
        int cq = 4 * hh + ((q + (hh >> 1)) & 3);
        float4 v; v.x = acc[q*4]; v.y = acc[q*4+1]; v.z = acc[q*4+2]; v.w = acc[q*4+3];
        *(float4*)&lacc[e][cq * 4] = v;
    }
    ls[e][hh] = s_part;
    __syncthreads();

    float outv = 0.f;
    if (t < 128) {
        const int hr = t >> 4, qq = (t >> 2) & 3, ww = t & 3;
        const int colmap = hr * 16 + (((qq + (hr >> 1)) & 3) << 2) + ww;
        float asum = 0.f;
#pragma unroll
        for (int jj = 0; jj < SLOTS; ++jj) asum += lacc[jj][colmap];
        float ssum = 0.f;
#pragma unroll
        for (int jj = 0; jj < SLOTS; ++jj) ssum += ls[jj][hr];

        outv = asum / ssum + gbias[t];
        outv = outv > 0.f ? outv : (__expf(outv) - 1.f);   // ELU(alpha=1)
        outv += hin[(size_t)d * HID + t];

        float s1 = outv, s2 = outv * outv;
#pragma unroll
        for (int o = 32; o; o >>= 1) {
            s1 += __shfl_down(s1, o);
            s2 += __shfl_down(s2, o);
        }
        if ((t & 63) == 0) { tmp[t >> 6] = s1; tmp[2 + (t >> 6)] = s2; }
    }
    __syncthreads();
    if (t < 128) {
        float mu  = (tmp[0] + tmp[1]) * (1.f / HID);
        float var = (tmp[2] + tmp[3]) * (1.f / HID) - mu * mu;
        float o = (outv - mu) * rsqrtf(var + LN_EPS) * g[t] + beta[t];
        hout[(size_t)d * HID + t] = o;
        if (hbout) hbout[(size_t)d * HID + t] = f2bf(o);
    }
}

extern "C" void kernel_launch(void* const* d_in, const int* in_sizes, int n_in,
                              void* d_out, int out_size, void* d_ws, size_t ws_size,
                              hipStream_t stream) {
    (void)in_sizes; (void)n_in; (void)out_size; (void)ws_size;
    const float* x        = (const float*)d_in[0];
    const int*   ei       = (const int*)  d_in[1];
    const float* W_in     = (const float*)d_in[2];
    const float* b_in     = (const float*)d_in[3];
    const float* ln_g     = (const float*)d_in[4];
    const float* ln_b     = (const float*)d_in[5];
    const float* Wl       = (const float*)d_in[6];
    const float* bl       = (const float*)d_in[7];
    const float* Wr       = (const float*)d_in[8];
    const float* br       = (const float*)d_in[9];
    const float* att      = (const float*)d_in[10];
    const float* gat_bias = (const float*)d_in[11];
    const float* norm_g   = (const float*)d_in[12];
    const float* norm_b   = (const float*)d_in[13];
    float* out_f = (float*)d_out;

    char* w = (char*)d_ws;
    float* h   = (float*)w;                         w += (size_t)N_NODES * HID * 4;
    int*   adj = (int*)w;                           w += (size_t)N_NODES * CAP * 4;
    int*   cnt = (int*)w;                           w += (size_t)N_NODES * 4;
    unsigned short* hb  = (unsigned short*)w;       w += (size_t)N_NODES * HID * 2;
    unsigned short* xlb = (unsigned short*)w;       w += (size_t)N_NODES * HID * 2;
    unsigned short* xrb = (unsigned short*)w;       w += (size_t)N_NODES * HID * 2;
    unsigned short* WtI = (unsigned short*)w;       w += (size_t)IN_DIM * HID * 2;
    unsigned short* Wlt = (unsigned short*)w;       w += (size_t)LAYERS * HID * HID * 2;
    unsigned short* Wrt = (unsigned short*)w;

    k_convert<<<512, 256, 0, stream>>>(W_in, Wl, Wr, WtI, Wlt, Wrt, cnt, adj);
    k_build<<<(NEDGE + 255) / 256, 256, 0, stream>>>(ei, cnt, adj);
    k_proj<<<N_NODES / 32, 128, 0, stream>>>(x, WtI, b_in, ln_g, ln_b, h, hb);

    for (int L = 0; L < LAYERS; ++L) {
        k_xlxr<<<N_NODES / 32, 128, 0, stream>>>(
            hb, Wlt + (size_t)L * HID * HID, Wrt + (size_t)L * HID * HID,
            bl + (size_t)L * HID, br + (size_t)L * HID, xlb, xrb);
        float*          hout   = (L == LAYERS - 1) ? out_f : h;
        unsigned short* hbnext = (L == LAYERS - 1) ? (unsigned short*)nullptr : hb;
        k_gat<<<N_NODES, 256, 0, stream>>>(
            xlb, xrb, adj, cnt,
            att + (size_t)L * HEADS * C_DIM, gat_bias + (size_t)L * HID,
            norm_g + (size_t)L * HID, norm_b + (size_t)L * HID, h, hout, hbnext);
    }
}

// Round 9
// 150.697 us; speedup vs baseline: 1.4007x; 1.4007x over previous
//
#include <hip/hip_runtime.h>
#include <math.h>

#define N_NODES 20000
#define IN_DIM  512
#define HID     128
#define HEADS   8
#define C_DIM   16
#define LAYERS  2
#define NEDGE   320000
#define NEG_SLOPE 0.2f
#define LN_EPS  1e-5f
#define CAP     64   // ELL capacity (incl. self loop); deg ~ Poisson(16)
#define SLOTS   16   // edge slots per k_gat chunk (128 thr: best measured config)

typedef __attribute__((ext_vector_type(8))) short short8;
typedef __attribute__((ext_vector_type(4))) float f32x4;

__device__ __forceinline__ unsigned short f2bf(float f) {
    unsigned int u = __float_as_uint(f);
    u += 0x7fffu + ((u >> 16) & 1u);
    return (unsigned short)(u >> 16);
}
__device__ __forceinline__ float bf2f(unsigned short s) {
    return __uint_as_float(((unsigned int)s) << 16);
}

// ------- one-time: weights -> bf16 transposed [n][k]; cnt=1 + self-loop in adj -------
__global__ __launch_bounds__(256) void k_convert(
    const float* __restrict__ W_in, const float* __restrict__ Wl, const float* __restrict__ Wr,
    unsigned short* __restrict__ WtI, unsigned short* __restrict__ Wlt, unsigned short* __restrict__ Wrt,
    int* __restrict__ cnt, int* __restrict__ adj)
{
    int i = blockIdx.x * 256 + threadIdx.x;
    if (i < N_NODES) { cnt[i] = 1; adj[(size_t)i * CAP] = i; }   // self loop at slot 0
    if (i < 65536) {                      // WtI[128][512]
        int n = i >> 9, k = i & 511;
        WtI[i] = f2bf(W_in[k * HID + n]);
    } else if (i < 98304) {               // Wlt[L][128][128]
        int r = i - 65536;
        int L = r >> 14, q = r & 16383;
        int n = q >> 7, k = q & 127;
        Wlt[r] = f2bf(Wl[L * 16384 + k * HID + n]);
    } else if (i < 131072) {              // Wrt[L][128][128]
        int r = i - 98304;
        int L = r >> 14, q = r & 16383;
        int n = q >> 7, k = q & 127;
        Wrt[r] = f2bf(Wr[L * 16384 + k * HID + n]);
    }
}

__global__ __launch_bounds__(256) void k_build(
    const int* __restrict__ ei, int* __restrict__ cnt, int* __restrict__ adj)
{
    int e = blockIdx.x * 256 + threadIdx.x;
    if (e >= NEDGE) return;
    int src = ei[e];
    int dst = ei[NEDGE + e];
    int r = atomicAdd(&cnt[dst], 1);
    if (r < CAP) adj[(size_t)dst * CAP + r] = src;
}

// ------- input proj MFMA: hb = bf16(relu(LN(x @ W_in + b))) -------
__global__ __launch_bounds__(128) void k_proj(
    const float* __restrict__ x, const unsigned short* __restrict__ WtI,
    const float* __restrict__ b, const float* __restrict__ g, const float* __restrict__ beta,
    unsigned short* __restrict__ hb)
{
    __shared__ unsigned short wlds[128][136];   // [n][k-chunk]
    __shared__ unsigned short xtile[32][136];   // [row][k-chunk] bf16
    const int tid = threadIdx.x;
    const int wid = tid >> 6;
    const int l   = tid & 63;
    const int grp = l >> 4;
    const int ln  = l & 15;
    const int row0 = blockIdx.x * 32;

    f32x4 acc[8];
#pragma unroll
    for (int j = 0; j < 8; ++j) acc[j] = (f32x4){0.f, 0.f, 0.f, 0.f};

    const int sr = tid >> 4;
    const int sc = (tid & 15) * 8;
    const int xrr = tid >> 2;            // x staging: row
    const int xcc = (tid & 3) * 32;      // x staging: col base

    for (int kc = 0; kc < 4; ++kc) {
        __syncthreads();
#pragma unroll
        for (int rr = sr; rr < 128; rr += 8)
            *(short8*)&wlds[rr][sc] = *(const short8*)&WtI[rr * IN_DIM + kc * 128 + sc];
        {
            const float4* ps = (const float4*)&x[(size_t)(row0 + xrr) * IN_DIM + kc * 128 + xcc];
#pragma unroll
            for (int q = 0; q < 4; ++q) {
                float4 va = ps[2 * q], vb = ps[2 * q + 1];
                short8 o;
                o[0] = (short)f2bf(va.x); o[1] = (short)f2bf(va.y);
                o[2] = (short)f2bf(va.z); o[3] = (short)f2bf(va.w);
                o[4] = (short)f2bf(vb.x); o[5] = (short)f2bf(vb.y);
                o[6] = (short)f2bf(vb.z); o[7] = (short)f2bf(vb.w);
                *(short8*)&xtile[xrr][xcc + q * 8] = o;
            }
        }
        __syncthreads();
#pragma unroll
        for (int ks = 0; ks < 4; ++ks) {
            short8 a = *(short8*)&xtile[wid * 16 + ln][ks * 32 + grp * 8];
#pragma unroll
            for (int j = 0; j < 8; ++j) {
                short8 bf = *(short8*)&wlds[j * 16 + ln][ks * 32 + grp * 8];
                acc[j] = __builtin_amdgcn_mfma_f32_16x16x32_bf16(a, bf, acc[j], 0, 0, 0);
            }
        }
    }
    // epilogue: +bias, LN over 128 cols, ReLU
    float s1[4] = {0, 0, 0, 0}, s2[4] = {0, 0, 0, 0};
#pragma unroll
    for (int j = 0; j < 8; ++j) {
        float bb = b[j * 16 + ln];
#pragma unroll
        for (int r = 0; r < 4; ++r) {
            float v = acc[j][r] + bb;
            acc[j][r] = v;
            s1[r] += v; s2[r] += v * v;
        }
    }
#pragma unroll
    for (int r = 0; r < 4; ++r) {
#pragma unroll
        for (int off = 8; off; off >>= 1) {
            s1[r] += __shfl_xor(s1[r], off);
            s2[r] += __shfl_xor(s2[r], off);
        }
    }
#pragma unroll
    for (int r = 0; r < 4; ++r) {
        float mu  = s1[r] * (1.f / HID);
        float var = s2[r] * (1.f / HID) - mu * mu;
        float rs  = rsqrtf(var + LN_EPS);
        int row = row0 + wid * 16 + grp * 4 + r;
#pragma unroll
        for (int j = 0; j < 8; ++j) {
            int c = j * 16 + ln;
            float o = (acc[j][r] - mu) * rs * g[c] + beta[c];
            hb[(size_t)row * HID + c] = f2bf(fmaxf(o, 0.f));
        }
    }
}

// ------- per-layer MFMA: xlb = bf16(hb@Wl + bl) ; xrb = bf16(hb@Wr + br) -------
__global__ __launch_bounds__(128) void k_xlxr(
    const unsigned short* __restrict__ hb,
    const unsigned short* __restrict__ Wlt, const unsigned short* __restrict__ Wrt,
    const float* __restrict__ bl, const float* __restrict__ br,
    unsigned short* __restrict__ xlb, unsigned short* __restrict__ xrb)
{
    __shared__ unsigned short wl_lds[128][136];
    __shared__ unsigned short wr_lds[128][136];
    const int tid = threadIdx.x;
    const int wid = tid >> 6;
    const int l   = tid & 63;
    const int grp = l >> 4;
    const int ln  = l & 15;
    const int row0 = blockIdx.x * 32;
    const int arow = row0 + wid * 16 + ln;

    const int sr = tid >> 4;
    const int sc = (tid & 15) * 8;
#pragma unroll
    for (int rr = sr; rr < 128; rr += 8) {
        *(short8*)&wl_lds[rr][sc] = *(const short8*)&Wlt[rr * HID + sc];
        *(short8*)&wr_lds[rr][sc] = *(const short8*)&Wrt[rr * HID + sc];
    }
    __syncthreads();

    f32x4 aL[8], aR[8];
#pragma unroll
    for (int j = 0; j < 8; ++j) {
        aL[j] = (f32x4){0.f, 0.f, 0.f, 0.f};
        aR[j] = (f32x4){0.f, 0.f, 0.f, 0.f};
    }
#pragma unroll
    for (int ks = 0; ks < 4; ++ks) {
        const int kk = ks * 32 + grp * 8;
        short8 a = *(const short8*)&hb[(size_t)arow * HID + kk];
#pragma unroll
        for (int j = 0; j < 8; ++j) {
            short8 b8l = *(short8*)&wl_lds[j * 16 + ln][kk];
            aL[j] = __builtin_amdgcn_mfma_f32_16x16x32_bf16(a, b8l, aL[j], 0, 0, 0);
            short8 b8r = *(short8*)&wr_lds[j * 16 + ln][kk];
            aR[j] = __builtin_amdgcn_mfma_f32_16x16x32_bf16(a, b8r, aR[j], 0, 0, 0);
        }
    }
#pragma unroll
    for (int r = 0; r < 4; ++r) {
        int row = row0 + wid * 16 + grp * 4 + r;
#pragma unroll
        for (int j = 0; j < 8; ++j) {
            int c = j * 16 + ln;
            xlb[(size_t)row * HID + c] = f2bf(aL[j][r] + bl[c]);
            xrb[(size_t)row * HID + c] = f2bf(aR[j][r] + br[c]);
        }
    }
}

// ------- fused GAT layer: 16 slots x 8 heads, folded self-loop, swizzled reduce -------
// thread (e,hh) = (t>>3, t&7): edge-slot e (0..15), head hh, channels [hh*16, hh*16+16)
__global__ __launch_bounds__(128) void k_gat(
    const unsigned short* __restrict__ xlb, const unsigned short* __restrict__ xrb,
    const int* __restrict__ adj, const int* __restrict__ cnt,
    const float* __restrict__ att, const float* __restrict__ gbias,
    const float* __restrict__ g, const float* __restrict__ beta,
    const unsigned short* __restrict__ hbin, float* __restrict__ hout,
    unsigned short* __restrict__ hbout)
{
    __shared__ int   adjs[CAP];
    __shared__ float lacc[SLOTS][132];   // row stride 33 float4s (odd) -> bank spread
    __shared__ float ls[SLOTS][HEADS];
    __shared__ float tmp[4];
    const int d  = blockIdx.x;
    const int t  = threadIdx.x;
    const int e  = t >> 3;
    const int hh = t & 7;
    const int cb = hh * 16;

    const int nj = min(cnt[d], CAP);     // includes self loop at slot 0
    if (t < nj) adjs[t] = adj[(size_t)d * CAP + t];   // truncated read
    __syncthreads();

    float av[16], rv[16];
#pragma unroll
    for (int q = 0; q < 4; ++q) {
        float4 a4 = *(const float4*)&att[cb + q * 4];
        av[q*4+0] = a4.x; av[q*4+1] = a4.y; av[q*4+2] = a4.z; av[q*4+3] = a4.w;
    }
    {
        const short8* pr = (const short8*)&xrb[(size_t)d * HID + cb];
        short8 r0 = pr[0], r1 = pr[1];
#pragma unroll
        for (int q = 0; q < 8; ++q) {
            rv[q]     = bf2f((unsigned short)r0[q]);
            rv[8 + q] = bf2f((unsigned short)r1[q]);
        }
    }

    float acc[16];
#pragma unroll
    for (int q = 0; q < 16; ++q) acc[q] = 0.f;
    float s_part = 0.f;

    const int nchunk = (nj + SLOTS - 1) >> 4;
    for (int ch = 0; ch < nchunk; ++ch) {
        int j = ch * SLOTS + e;
        int srcn = adjs[j < nj ? j : 0];
        const short8* px = (const short8*)&xlb[(size_t)srcn * HID + cb];
        short8 x0 = px[0], x1 = px[1];
        float xf[16];
#pragma unroll
        for (int q = 0; q < 8; ++q) {
            xf[q]     = bf2f((unsigned short)x0[q]);
            xf[8 + q] = bf2f((unsigned short)x1[q]);
        }
        float ll = 0.f;
#pragma unroll
        for (int q = 0; q < 16; ++q) {
            float u = xf[q] + rv[q];
            u = fmaxf(u, NEG_SLOPE * u);
            ll = fmaf(av[q], u, ll);
        }
        // exp without max-shift: logits O(+-10), identical softmax result
        float p = (j < nj) ? __expf(ll) : 0.f;
        s_part += p;
#pragma unroll
        for (int q = 0; q < 16; ++q) acc[q] = fmaf(p, xf[q], acc[q]);
    }

    // swizzled-column float4 store: content quad q of head hh at physical quad
    // 4*hh + ((q+(hh>>1))&3) -> 8 lanes per 16B bank-group, conflict-free
#pragma unroll
    for (int q = 0; q < 4; ++q) {
        int cq = 4 * hh + ((q + (hh >> 1)) & 3);
        float4 v; v.x = acc[q*4]; v.y = acc[q*4+1]; v.z = acc[q*4+2]; v.w = acc[q*4+3];
        *(float4*)&lacc[e][cq * 4] = v;
    }
    ls[e][hh] = s_part;
    __syncthreads();

    // thread t owns channel t
    const int hr = t >> 4, qq = (t >> 2) & 3, ww = t & 3;
    const int colmap = hr * 16 + (((qq + (hr >> 1)) & 3) << 2) + ww;
    float asum = 0.f;
#pragma unroll
    for (int jj = 0; jj < SLOTS; ++jj) asum += lacc[jj][colmap];
    float ssum = 0.f;
#pragma unroll
    for (int jj = 0; jj < SLOTS; ++jj) ssum += ls[jj][hr];

    float outv = asum / ssum + gbias[t];
    outv = outv > 0.f ? outv : (__expf(outv) - 1.f);   // ELU(alpha=1)
    outv += bf2f(hbin[(size_t)d * HID + t]);           // residual (bf16)

    float s1 = outv, s2 = outv * outv;
#pragma unroll
    for (int o = 32; o; o >>= 1) {
        s1 += __shfl_down(s1, o);
        s2 += __shfl_down(s2, o);
    }
    if ((t & 63) == 0) { tmp[t >> 6] = s1; tmp[2 + (t >> 6)] = s2; }
    __syncthreads();
    float mu  = (tmp[0] + tmp[1]) * (1.f / HID);
    float var = (tmp[2] + tmp[3]) * (1.f / HID) - mu * mu;
    float o = (outv - mu) * rsqrtf(var + LN_EPS) * g[t] + beta[t];
    if (hout)  hout [(size_t)d * HID + t] = o;
    if (hbout) hbout[(size_t)d * HID + t] = f2bf(o);
}

extern "C" void kernel_launch(void* const* d_in, const int* in_sizes, int n_in,
                              void* d_out, int out_size, void* d_ws, size_t ws_size,
                              hipStream_t stream) {
    (void)in_sizes; (void)n_in; (void)out_size; (void)ws_size;
    const float* x        = (const float*)d_in[0];
    const int*   ei       = (const int*)  d_in[1];
    const float* W_in     = (const float*)d_in[2];
    const float* b_in     = (const float*)d_in[3];
    const float* ln_g     = (const float*)d_in[4];
    const float* ln_b     = (const float*)d_in[5];
    const float* Wl       = (const float*)d_in[6];
    const float* bl       = (const float*)d_in[7];
    const float* Wr       = (const float*)d_in[8];
    const float* br       = (const float*)d_in[9];
    const float* att      = (const float*)d_in[10];
    const float* gat_bias = (const float*)d_in[11];
    const float* norm_g   = (const float*)d_in[12];
    const float* norm_b   = (const float*)d_in[13];
    float* out_f = (float*)d_out;

    char* w = (char*)d_ws;
    int*   adj = (int*)w;                           w += (size_t)N_NODES * CAP * 4;
    int*   cnt = (int*)w;                           w += (size_t)N_NODES * 4;
    unsigned short* hb  = (unsigned short*)w;       w += (size_t)N_NODES * HID * 2;
    unsigned short* xlb = (unsigned short*)w;       w += (size_t)N_NODES * HID * 2;
    unsigned short* xrb = (unsigned short*)w;       w += (size_t)N_NODES * HID * 2;
    unsigned short* WtI = (unsigned short*)w;       w += (size_t)IN_DIM * HID * 2;
    unsigned short* Wlt = (unsigned short*)w;       w += (size_t)LAYERS * HID * HID * 2;
    unsigned short* Wrt = (unsigned short*)w;

    k_convert<<<512, 256, 0, stream>>>(W_in, Wl, Wr, WtI, Wlt, Wrt, cnt, adj);
    k_build<<<(NEDGE + 255) / 256, 256, 0, stream>>>(ei, cnt, adj);
    k_proj<<<N_NODES / 32, 128, 0, stream>>>(x, WtI, b_in, ln_g, ln_b, hb);

    for (int L = 0; L < LAYERS; ++L) {
        k_xlxr<<<N_NODES / 32, 128, 0, stream>>>(
            hb, Wlt + (size_t)L * HID * HID, Wrt + (size_t)L * HID * HID,
            bl + (size_t)L * HID, br + (size_t)L * HID, xlb, xrb);
        float*          hout   = (L == LAYERS - 1) ? out_f : (float*)nullptr;
        unsigned short* hbnext = (L == LAYERS - 1) ? (unsigned short*)nullptr : hb;
        k_gat<<<N_NODES, 128, 0, stream>>>(
            xlb, xrb, adj, cnt,
            att + (size_t)L * HEADS * C_DIM, gat_bias + (size_t)L * HID,
            norm_g + (size_t)L * HID, norm_b + (size_t)L * HID, hb, hout, hbnext);
    }
}

// Round 10
// 133.769 us; speedup vs baseline: 1.5780x; 1.1265x over previous
//
#include <hip/hip_runtime.h>
#include <math.h>

#define N_NODES 20000
#define IN_DIM  512
#define HID     128
#define HEADS   8
#define C_DIM   16
#define LAYERS  2
#define NEDGE   320000
#define NEG_SLOPE 0.2f
#define LN_EPS  1e-5f
#define CAP     64   // ELL capacity (incl. self loop); deg ~ Poisson(16)
#define SLOTS   16   // edge slots per k_gat chunk

#define PROJ_BLKS  625                         // N_NODES/32
#define EDGE_BLKS  ((NEDGE + 127) / 128)       // 2500
#define SELF_BLKS  ((N_NODES + 127) / 128)     // 157

typedef __attribute__((ext_vector_type(8))) short short8;
typedef __attribute__((ext_vector_type(4))) float f32x4;

__device__ __forceinline__ unsigned short f2bf(float f) {
    unsigned int u = __float_as_uint(f);
    u += 0x7fffu + ((u >> 16) & 1u);
    return (unsigned short)(u >> 16);
}
__device__ __forceinline__ float bf2f(unsigned short s) {
    return __uint_as_float(((unsigned int)s) << 16);
}

// ------- one-time: cnt=0; weights -> bf16 transposed [n][k] -------
__global__ __launch_bounds__(256) void k_convert(
    const float* __restrict__ W_in, const float* __restrict__ Wl, const float* __restrict__ Wr,
    unsigned short* __restrict__ WtI, unsigned short* __restrict__ Wlt, unsigned short* __restrict__ Wrt,
    int* __restrict__ cnt)
{
    int i = blockIdx.x * 256 + threadIdx.x;
    if (i < N_NODES) cnt[i] = 0;
    if (i < 65536) {                      // WtI[128][512]
        int n = i >> 9, k = i & 511;
        WtI[i] = f2bf(W_in[k * HID + n]);
    } else if (i < 98304) {               // Wlt[L][128][128]
        int r = i - 65536;
        int L = r >> 14, q = r & 16383;
        int n = q >> 7, k = q & 127;
        Wlt[r] = f2bf(Wl[L * 16384 + k * HID + n]);
    } else if (i < 131072) {              // Wrt[L][128][128]
        int r = i - 98304;
        int L = r >> 14, q = r & 16383;
        int n = q >> 7, k = q & 127;
        Wrt[r] = f2bf(Wr[L * 16384 + k * HID + n]);
    }
}

// ------- fused: input proj (blocks [0,625)) + edge build + self-loop insert -------
// proj occupies ~2.4 blocks/CU; build blocks backfill the idle CUs concurrently.
__global__ __launch_bounds__(128) void k_fused0(
    const float* __restrict__ x, const unsigned short* __restrict__ WtI,
    const float* __restrict__ b, const float* __restrict__ g, const float* __restrict__ beta,
    unsigned short* __restrict__ hb,
    const int* __restrict__ ei, int* __restrict__ cnt, int* __restrict__ adj)
{
    __shared__ unsigned short wlds[128][136];   // [n][k-chunk]
    __shared__ unsigned short xtile[32][136];   // [row][k-chunk] bf16
    const int bid = blockIdx.x;
    const int tid = threadIdx.x;

    if (bid >= PROJ_BLKS) {
        if (bid < PROJ_BLKS + EDGE_BLKS) {
            int e = (bid - PROJ_BLKS) * 128 + tid;
            if (e < NEDGE) {
                int src = ei[e];
                int dst = ei[NEDGE + e];
                int r = atomicAdd(&cnt[dst], 1);
                if (r < CAP) adj[(unsigned)dst * CAP + r] = src;
            }
        } else {
            int i = (bid - PROJ_BLKS - EDGE_BLKS) * 128 + tid;
            if (i < N_NODES) {
                int r = atomicAdd(&cnt[i], 1);
                if (r < CAP) adj[(unsigned)i * CAP + r] = i;
            }
        }
        return;
    }

    const int wid = tid >> 6;
    const int l   = tid & 63;
    const int grp = l >> 4;
    const int ln  = l & 15;
    const int row0 = bid * 32;

    f32x4 acc[8];
#pragma unroll
    for (int j = 0; j < 8; ++j) acc[j] = (f32x4){0.f, 0.f, 0.f, 0.f};

    const int sr = tid >> 4;
    const int sc = (tid & 15) * 8;
    const int xrr = tid >> 2;            // x staging: row
    const int xcc = (tid & 3) * 32;      // x staging: col base

    for (int kc = 0; kc < 4; ++kc) {
        __syncthreads();
#pragma unroll
        for (int rr = sr; rr < 128; rr += 8)
            *(short8*)&wlds[rr][sc] = *(const short8*)&WtI[rr * IN_DIM + kc * 128 + sc];
        {
            const float4* ps = (const float4*)&x[(unsigned)(row0 + xrr) * IN_DIM + kc * 128 + xcc];
#pragma unroll
            for (int q = 0; q < 4; ++q) {
                float4 va = ps[2 * q], vb = ps[2 * q + 1];
                short8 o;
                o[0] = (short)f2bf(va.x); o[1] = (short)f2bf(va.y);
                o[2] = (short)f2bf(va.z); o[3] = (short)f2bf(va.w);
                o[4] = (short)f2bf(vb.x); o[5] = (short)f2bf(vb.y);
                o[6] = (short)f2bf(vb.z); o[7] = (short)f2bf(vb.w);
                *(short8*)&xtile[xrr][xcc + q * 8] = o;
            }
        }
        __syncthreads();
#pragma unroll
        for (int ks = 0; ks < 4; ++ks) {
            short8 a = *(short8*)&xtile[wid * 16 + ln][ks * 32 + grp * 8];
#pragma unroll
            for (int j = 0; j < 8; ++j) {
                short8 bf = *(short8*)&wlds[j * 16 + ln][ks * 32 + grp * 8];
                acc[j] = __builtin_amdgcn_mfma_f32_16x16x32_bf16(a, bf, acc[j], 0, 0, 0);
            }
        }
    }
    // epilogue: +bias, LN over 128 cols, ReLU
    float s1[4] = {0, 0, 0, 0}, s2[4] = {0, 0, 0, 0};
#pragma unroll
    for (int j = 0; j < 8; ++j) {
        float bb = b[j * 16 + ln];
#pragma unroll
        for (int r = 0; r < 4; ++r) {
            float v = acc[j][r] + bb;
            acc[j][r] = v;
            s1[r] += v; s2[r] += v * v;
        }
    }
#pragma unroll
    for (int r = 0; r < 4; ++r) {
#pragma unroll
        for (int off = 8; off; off >>= 1) {
            s1[r] += __shfl_xor(s1[r], off);
            s2[r] += __shfl_xor(s2[r], off);
        }
    }
#pragma unroll
    for (int r = 0; r < 4; ++r) {
        float mu  = s1[r] * (1.f / HID);
        float var = s2[r] * (1.f / HID) - mu * mu;
        float rs  = rsqrtf(var + LN_EPS);
        int row = row0 + wid * 16 + grp * 4 + r;
#pragma unroll
        for (int j = 0; j < 8; ++j) {
            int c = j * 16 + ln;
            float o = (acc[j][r] - mu) * rs * g[c] + beta[c];
            hb[(unsigned)row * HID + c] = f2bf(fmaxf(o, 0.f));
        }
    }
}

// ------- per-layer MFMA: xlb = bf16(hb@Wl + bl) ; xrb = bf16(hb@Wr + br) -------
__global__ __launch_bounds__(128) void k_xlxr(
    const unsigned short* __restrict__ hb,
    const unsigned short* __restrict__ Wlt, const unsigned short* __restrict__ Wrt,
    const float* __restrict__ bl, const float* __restrict__ br,
    unsigned short* __restrict__ xlb, unsigned short* __restrict__ xrb)
{
    __shared__ unsigned short wl_lds[128][136];
    __shared__ unsigned short wr_lds[128][136];
    const int tid = threadIdx.x;
    const int wid = tid >> 6;
    const int l   = tid & 63;
    const int grp = l >> 4;
    const int ln  = l & 15;
    const int row0 = blockIdx.x * 32;
    const int arow = row0 + wid * 16 + ln;

    const int sr = tid >> 4;
    const int sc = (tid & 15) * 8;
#pragma unroll
    for (int rr = sr; rr < 128; rr += 8) {
        *(short8*)&wl_lds[rr][sc] = *(const short8*)&Wlt[rr * HID + sc];
        *(short8*)&wr_lds[rr][sc] = *(const short8*)&Wrt[rr * HID + sc];
    }
    __syncthreads();

    f32x4 aL[8], aR[8];
#pragma unroll
    for (int j = 0; j < 8; ++j) {
        aL[j] = (f32x4){0.f, 0.f, 0.f, 0.f};
        aR[j] = (f32x4){0.f, 0.f, 0.f, 0.f};
    }
#pragma unroll
    for (int ks = 0; ks < 4; ++ks) {
        const int kk = ks * 32 + grp * 8;
        short8 a = *(const short8*)&hb[(unsigned)arow * HID + kk];
#pragma unroll
        for (int j = 0; j < 8; ++j) {
            short8 b8l = *(short8*)&wl_lds[j * 16 + ln][kk];
            aL[j] = __builtin_amdgcn_mfma_f32_16x16x32_bf16(a, b8l, aL[j], 0, 0, 0);
            short8 b8r = *(short8*)&wr_lds[j * 16 + ln][kk];
            aR[j] = __builtin_amdgcn_mfma_f32_16x16x32_bf16(a, b8r, aR[j], 0, 0, 0);
        }
    }
#pragma unroll
    for (int r = 0; r < 4; ++r) {
        int row = row0 + wid * 16 + grp * 4 + r;
#pragma unroll
        for (int j = 0; j < 8; ++j) {
            int c = j * 16 + ln;
            xlb[(unsigned)row * HID + c] = f2bf(aL[j][r] + bl[c]);
            xrb[(unsigned)row * HID + c] = f2bf(aR[j][r] + br[c]);
        }
    }
}

// per-slot work: convert gathered row, logit, exp, accumulate
#define PROC(xa, xb, live) do {                                             \
    float xf[16];                                                           \
    _Pragma("unroll")                                                       \
    for (int q = 0; q < 8; ++q) {                                           \
        xf[q]     = bf2f((unsigned short)(xa)[q]);                          \
        xf[8 + q] = bf2f((unsigned short)(xb)[q]);                          \
    }                                                                       \
    float ll = 0.f;                                                         \
    _Pragma("unroll")                                                       \
    for (int q = 0; q < 16; ++q) {                                          \
        float u = xf[q] + rv[q];                                            \
        u = fmaxf(u, NEG_SLOPE * u);                                        \
        ll = fmaf(av[q], u, ll);                                            \
    }                                                                       \
    float p = (live) ? __expf(ll) : 0.f;                                    \
    s_part += p;                                                            \
    _Pragma("unroll")                                                       \
    for (int q = 0; q < 16; ++q) acc[q] = fmaf(p, xf[q], acc[q]);           \
} while (0)

// ------- fused GAT layer: 16 slots x 8 heads, dual-chunk hoist, swizzled reduce -------
// thread (e,hh) = (t>>3, t&7): edge-slot e (0..15), head hh, channels [hh*16, hh*16+16)
__global__ __launch_bounds__(128) void k_gat(
    const unsigned short* __restrict__ xlb, const unsigned short* __restrict__ xrb,
    const int* __restrict__ adj, const int* __restrict__ cnt,
    const float* __restrict__ att, const float* __restrict__ gbias,
    const float* __restrict__ g, const float* __restrict__ beta,
    const unsigned short* __restrict__ hbin, float* __restrict__ hout,
    unsigned short* __restrict__ hbout)
{
    __shared__ int   adjs[CAP];
    __shared__ float lacc[SLOTS][132];   // row stride 33 float4s (odd) -> bank spread
    __shared__ float ls[SLOTS][HEADS];
    __shared__ float tmp[4];
    const int d  = blockIdx.x;
    const int t  = threadIdx.x;
    const int e  = t >> 3;
    const int hh = t & 7;
    const int cb = hh * 16;

    const int nj = min(cnt[d], CAP);     // includes self loop (atomic insert)
    if (t < nj) adjs[t] = adj[(unsigned)d * CAP + t];
    __syncthreads();

    float av[16], rv[16];
#pragma unroll
    for (int q = 0; q < 4; ++q) {
        float4 a4 = *(const float4*)&att[cb + q * 4];
        av[q*4+0] = a4.x; av[q*4+1] = a4.y; av[q*4+2] = a4.z; av[q*4+3] = a4.w;
    }
    {
        const short8* pr = (const short8*)&xrb[(unsigned)d * HID + cb];
        short8 r0 = pr[0], r1 = pr[1];
#pragma unroll
        for (int q = 0; q < 8; ++q) {
            rv[q]     = bf2f((unsigned short)r0[q]);
            rv[8 + q] = bf2f((unsigned short)r1[q]);
        }
    }

    float acc[16];
#pragma unroll
    for (int q = 0; q < 16; ++q) acc[q] = 0.f;
    float s_part = 0.f;

    // chunk 0 gather (always issued)
    unsigned o0 = (unsigned)(adjs[e < nj ? e : 0] * HID) + cb;
    short8 xa0 = *(const short8*)&xlb[o0];
    short8 xb0 = *(const short8*)&xlb[o0 + 8];

    if (nj > SLOTS) {
        // chunk 1 gather issued BEFORE chunk-0 compute (latency overlap)
        int j1 = SLOTS + e;
        unsigned o1 = (unsigned)(adjs[j1 < nj ? j1 : 0] * HID) + cb;
        short8 xa1 = *(const short8*)&xlb[o1];
        short8 xb1 = *(const short8*)&xlb[o1 + 8];
        PROC(xa0, xb0, true);            // nj>16 -> all 16 slots of chunk 0 live
        PROC(xa1, xb1, j1 < nj);
        for (int ch = 2; (ch << 4) < nj; ++ch) {   // rare: nj > 32 (~0.04%)
            int j = (ch << 4) + e;
            unsigned oj = (unsigned)(adjs[j < nj ? j : 0] * HID) + cb;
            short8 xaj = *(const short8*)&xlb[oj];
            short8 xbj = *(const short8*)&xlb[oj + 8];
            PROC(xaj, xbj, j < nj);
        }
    } else {
        PROC(xa0, xb0, e < nj);
    }

    // swizzled-column float4 store: content quad q of head hh at physical quad
    // 4*hh + ((q+(hh>>1))&3) -> 8 lanes per 16B bank-group, conflict-free
#pragma unroll
    for (int q = 0; q < 4; ++q) {
        int cq = 4 * hh + ((q + (hh >> 1)) & 3);
        float4 v; v.x = acc[q*4]; v.y = acc[q*4+1]; v.z = acc[q*4+2]; v.w = acc[q*4+3];
        *(float4*)&lacc[e][cq * 4] = v;
    }
    ls[e][hh] = s_part;
    __syncthreads();

    // thread t owns channel t
    const int hr = t >> 4, qq = (t >> 2) & 3, ww = t & 3;
    const int colmap = hr * 16 + (((qq + (hr >> 1)) & 3) << 2) + ww;
    float asum = 0.f;
#pragma unroll
    for (int jj = 0; jj < SLOTS; ++jj) asum += lacc[jj][colmap];
    float ssum = 0.f;
#pragma unroll
    for (int jj = 0; jj < SLOTS; ++jj) ssum += ls[jj][hr];

    float outv = asum / ssum + gbias[t];
    outv = outv > 0.f ? outv : (__expf(outv) - 1.f);   // ELU(alpha=1)
    outv += bf2f(hbin[(unsigned)d * HID + t]);         // residual (bf16)

    float s1 = outv, s2 = outv * outv;
#pragma unroll
    for (int o = 32; o; o >>= 1) {
        s1 += __shfl_down(s1, o);
        s2 += __shfl_down(s2, o);
    }
    if ((t & 63) == 0) { tmp[t >> 6] = s1; tmp[2 + (t >> 6)] = s2; }
    __syncthreads();
    float mu  = (tmp[0] + tmp[1]) * (1.f / HID);
    float var = (tmp[2] + tmp[3]) * (1.f / HID) - mu * mu;
    float o = (outv - mu) * rsqrtf(var + LN_EPS) * g[t] + beta[t];
    if (hout)  hout [(unsigned)d * HID + t] = o;
    if (hbout) hbout[(unsigned)d * HID + t] = f2bf(o);
}

extern "C" void kernel_launch(void* const* d_in, const int* in_sizes, int n_in,
                              void* d_out, int out_size, void* d_ws, size_t ws_size,
                              hipStream_t stream) {
    (void)in_sizes; (void)n_in; (void)out_size; (void)ws_size;
    const float* x        = (const float*)d_in[0];
    const int*   ei       = (const int*)  d_in[1];
    const float* W_in     = (const float*)d_in[2];
    const float* b_in     = (const float*)d_in[3];
    const float* ln_g     = (const float*)d_in[4];
    const float* ln_b     = (const float*)d_in[5];
    const float* Wl       = (const float*)d_in[6];
    const float* bl       = (const float*)d_in[7];
    const float* Wr       = (const float*)d_in[8];
    const float* br       = (const float*)d_in[9];
    const float* att      = (const float*)d_in[10];
    const float* gat_bias = (const float*)d_in[11];
    const float* norm_g   = (const float*)d_in[12];
    const float* norm_b   = (const float*)d_in[13];
    float* out_f = (float*)d_out;

    char* w = (char*)d_ws;
    int*   adj = (int*)w;                           w += (size_t)N_NODES * CAP * 4;
    int*   cnt = (int*)w;                           w += (size_t)N_NODES * 4;
    unsigned short* hb  = (unsigned short*)w;       w += (size_t)N_NODES * HID * 2;
    unsigned short* xlb = (unsigned short*)w;       w += (size_t)N_NODES * HID * 2;
    unsigned short* xrb = (unsigned short*)w;       w += (size_t)N_NODES * HID * 2;
    unsigned short* WtI = (unsigned short*)w;       w += (size_t)IN_DIM * HID * 2;
    unsigned short* Wlt = (unsigned short*)w;       w += (size_t)LAYERS * HID * HID * 2;
    unsigned short* Wrt = (unsigned short*)w;

    k_convert<<<512, 256, 0, stream>>>(W_in, Wl, Wr, WtI, Wlt, Wrt, cnt);
    k_fused0<<<PROJ_BLKS + EDGE_BLKS + SELF_BLKS, 128, 0, stream>>>(
        x, WtI, b_in, ln_g, ln_b, hb, ei, cnt, adj);

    for (int L = 0; L < LAYERS; ++L) {
        k_xlxr<<<N_NODES / 32, 128, 0, stream>>>(
            hb, Wlt + (size_t)L * HID * HID, Wrt + (size_t)L * HID * HID,
            bl + (size_t)L * HID, br + (size_t)L * HID, xlb, xrb);
        float*          hout   = (L == LAYERS - 1) ? out_f : (float*)nullptr;
        unsigned short* hbnext = (L == LAYERS - 1) ? (unsigned short*)nullptr : hb;
        k_gat<<<N_NODES, 128, 0, stream>>>(
            xlb, xrb, adj, cnt,
            att + (size_t)L * HEADS * C_DIM, gat_bias + (size_t)L * HID,
            norm_g + (size_t)L * HID, norm_b + (size_t)L * HID, hb, hout, hbnext);
    }
}